// Round 4
// baseline (1463.116 us; speedup 1.0000x reference)
//
#include <hip/hip_runtime.h>
#include <stdint.h>

// HashEmbedder (Instant-NGP multires hash grid), 16 levels, F=2, T=2^19,
// N = 2^21 points.
//
// Round-4 structure (round-3 with compile fix: nontemporal builtins need
// native clang vector types, not HIP_vector_type):
//   pass 0: pack f32 tables -> bf16x2 (4B/entry, 2 MB/level).
//   pass 1: level-AT-A-TIME across the WHOLE machine (blockIdx-ordered:
//           level = b>>11). Each XCD's L2 replicates the current level's
//           2 MB table -> fine levels get aggregate 34.5 TB/s L2 BW
//           instead of round-2's pinned 1/8 share.
//   pass 2: transpose level-major [16][N] bf16x2 -> [N][32] f32.
// Falls back to simpler variants if ws_size is too small.

constexpr int kLevels = 16;
constexpr int kPoints = 1 << 21;
constexpr uint32_t kTableSize = 1u << 19;
constexpr uint32_t kMask = kTableSize - 1u;
constexpr int kChunksPerLevel = 2048;                     // one machine-fill
constexpr int kPtsPerChunk = kPoints / kChunksPerLevel;   // 1024
constexpr size_t kPackedBytes = (size_t)kLevels * kTableSize * 4;  // 32 MB
constexpr size_t kLvlOutBytes = (size_t)kLevels * kPoints * 4;     // 128 MB

typedef float f32x4 __attribute__((ext_vector_type(4)));  // native vec type

// floor(16 * b^i), b = exp(ln(32)/15) in f64 (boundary levels round up).
__constant__ float c_res[kLevels] = {
    16.f, 20.f, 25.f, 32.f, 40.f, 50.f, 64.f, 80.f,
    101.f, 128.f, 161.f, 203.f, 256.f, 322.f, 406.f, 512.f};

__device__ __forceinline__ uint32_t bf16_rtne_hi(float f) {
    uint32_t u = __float_as_uint(f);
    return (u + 0x7FFFu + ((u >> 16) & 1u)) >> 16;
}

// ---------------- pass 0: pack tables to bf16x2 ----------------
__global__ __launch_bounds__(256) void pack_tables_kernel(
    const float* __restrict__ tables, uint32_t* __restrict__ packed)
{
    const int i = blockIdx.x * 256 + threadIdx.x;  // 2 entries per thread
    const f32x4 v = __builtin_nontemporal_load(
        reinterpret_cast<const f32x4*>(tables) + i);
    uint2 o;
    o.x = bf16_rtne_hi(v.x) | (bf16_rtne_hi(v.y) << 16);
    o.y = bf16_rtne_hi(v.z) | (bf16_rtne_hi(v.w) << 16);
    reinterpret_cast<uint2*>(packed)[i] = o;
}

// ---------------- shared per-point level evaluation ----------------
__device__ __forceinline__ void eval_level(
    float px, float py, float pz, float r,
    const uint32_t* __restrict__ tab, float& a0, float& a1)
{
    const float tx = px * r, ty = py * r, tz = pz * r;
    const float fx = floorf(tx), fy = floorf(ty), fz = floorf(tz);
    const int bx = (int)fx, by = (int)fy, bz = (int)fz;
    const float rx = tx - fx, ry = ty - fy, rz = tz - fz;

    const uint32_t hx0 = (uint32_t)bx;
    const uint32_t hx1 = (uint32_t)(bx + 1);
    const uint32_t hy0 = (uint32_t)by * 2654435761u;
    const uint32_t hy1 = (uint32_t)(by + 1) * 2654435761u;
    const uint32_t hz0 = (uint32_t)bz * 805459861u;
    const uint32_t hz1 = (uint32_t)(bz + 1) * 805459861u;

    const float wx1 = rx, wx0 = 1.0f - rx;
    const float wy1 = ry, wy0 = 1.0f - ry;
    const float wz1 = rz, wz0 = 1.0f - rz;

    a0 = 0.0f; a1 = 0.0f;
#pragma unroll
    for (int c = 0; c < 8; ++c) {
        const uint32_t h = (((c & 4) ? hx1 : hx0) ^
                            ((c & 2) ? hy1 : hy0) ^
                            ((c & 1) ? hz1 : hz0)) & kMask;
        const uint32_t e = tab[h];
        const float w = ((c & 4) ? wx1 : wx0) *
                        ((c & 2) ? wy1 : wy0) *
                        ((c & 1) ? wz1 : wz0);
        a0 = fmaf(w, __uint_as_float(e << 16), a0);
        a1 = fmaf(w, __uint_as_float(e & 0xFFFF0000u), a1);
    }
}

// ---------------- pass 1: level-at-a-time, whole machine ----------------
__global__ __launch_bounds__(256) void level_pass_kernel(
    const float* __restrict__ x,
    const uint32_t* __restrict__ packed,
    uint32_t* __restrict__ lvl_out)
{
    const int b = blockIdx.x;
    const int level = b >> 11;            // blockIdx-ordered: one level fills
    const int chunk = b & (kChunksPerLevel - 1);  // the machine at a time

    const float r = c_res[level];
    const uint32_t* __restrict__ tab = packed + (size_t)level * kTableSize;
    uint32_t* __restrict__ w = lvl_out + (size_t)level * kPoints;

    const int n0 = chunk * kPtsPerChunk + threadIdx.x;
#pragma unroll
    for (int k = 0; k < kPtsPerChunk / 256; ++k) {
        const int n = n0 + k * 256;
        float px = fminf(fmaxf(x[3 * n + 0], 0.0f), 1.0f);
        float py = fminf(fmaxf(x[3 * n + 1], 0.0f), 1.0f);
        float pz = fminf(fmaxf(x[3 * n + 2], 0.0f), 1.0f);
        float a0, a1;
        eval_level(px, py, pz, r, tab, a0, a1);
        __builtin_nontemporal_store(bf16_rtne_hi(a0) | (bf16_rtne_hi(a1) << 16),
                                    &w[n]);
    }
}

// ---------------- pass 2: level-major bf16 -> [N][32] f32 ----------------
__global__ __launch_bounds__(256) void untile_kernel(
    const uint32_t* __restrict__ lvl_out, float* __restrict__ out)
{
    const int n = blockIdx.x * 256 + threadIdx.x;
    float vals[2 * kLevels];
#pragma unroll
    for (int l = 0; l < kLevels; ++l) {
        const uint32_t u =
            __builtin_nontemporal_load(&lvl_out[(size_t)l * kPoints + n]);
        vals[2 * l + 0] = __uint_as_float(u << 16);
        vals[2 * l + 1] = __uint_as_float(u & 0xFFFF0000u);
    }
    f32x4* o4 = reinterpret_cast<f32x4*>(out + (size_t)n * (2 * kLevels));
#pragma unroll
    for (int kq = 0; kq < 8; ++kq) {
        f32x4 v;
        v.x = vals[4 * kq + 0];
        v.y = vals[4 * kq + 1];
        v.z = vals[4 * kq + 2];
        v.w = vals[4 * kq + 3];
        __builtin_nontemporal_store(v, &o4[kq]);
    }
}

// ---------------- fallback: direct per-point kernel (f32 tables) --------
__global__ __launch_bounds__(256) void direct_kernel(
    const float* __restrict__ x,
    const float* __restrict__ tables,
    float* __restrict__ out)
{
    const int n = blockIdx.x * 256 + threadIdx.x;
    float px = fminf(fmaxf(x[3 * n + 0], 0.0f), 1.0f);
    float py = fminf(fmaxf(x[3 * n + 1], 0.0f), 1.0f);
    float pz = fminf(fmaxf(x[3 * n + 2], 0.0f), 1.0f);

    const float res_tab[kLevels] = {
        16.f, 20.f, 25.f, 32.f, 40.f, 50.f, 64.f, 80.f,
        101.f, 128.f, 161.f, 203.f, 256.f, 322.f, 406.f, 512.f};

    float acc[2 * kLevels];
#pragma unroll
    for (int l = 0; l < kLevels; ++l) {
        const float r = res_tab[l];
        const float tx = px * r, ty = py * r, tz = pz * r;
        const float fx = floorf(tx), fy = floorf(ty), fz = floorf(tz);
        const int bx = (int)fx, by = (int)fy, bz = (int)fz;
        const float rx = tx - fx, ry = ty - fy, rz = tz - fz;
        const uint32_t hx0 = (uint32_t)bx;
        const uint32_t hx1 = (uint32_t)(bx + 1);
        const uint32_t hy0 = (uint32_t)by * 2654435761u;
        const uint32_t hy1 = (uint32_t)(by + 1) * 2654435761u;
        const uint32_t hz0 = (uint32_t)bz * 805459861u;
        const uint32_t hz1 = (uint32_t)(bz + 1) * 805459861u;
        const float wx1 = rx, wx0 = 1.0f - rx;
        const float wy1 = ry, wy0 = 1.0f - ry;
        const float wz1 = rz, wz0 = 1.0f - rz;
        const float2* __restrict__ tab =
            reinterpret_cast<const float2*>(tables) + (size_t)l * kTableSize;
        float a0 = 0.0f, a1 = 0.0f;
#pragma unroll
        for (int c = 0; c < 8; ++c) {
            const uint32_t h = (((c & 4) ? hx1 : hx0) ^
                                ((c & 2) ? hy1 : hy0) ^
                                ((c & 1) ? hz1 : hz0)) & kMask;
            const float2 e = tab[h];
            const float w = ((c & 4) ? wx1 : wx0) *
                            ((c & 2) ? wy1 : wy0) *
                            ((c & 1) ? wz1 : wz0);
            a0 = fmaf(w, e.x, a0);
            a1 = fmaf(w, e.y, a1);
        }
        acc[2 * l + 0] = a0;
        acc[2 * l + 1] = a1;
    }
    float4* o4 = reinterpret_cast<float4*>(out + (size_t)n * (2 * kLevels));
#pragma unroll
    for (int kq = 0; kq < 8; ++kq) {
        o4[kq] = make_float4(acc[4 * kq + 0], acc[4 * kq + 1],
                             acc[4 * kq + 2], acc[4 * kq + 3]);
    }
}

// fallback middle variant: direct per-point kernel reading packed tables
__global__ __launch_bounds__(256) void direct_packed_kernel(
    const float* __restrict__ x,
    const uint32_t* __restrict__ packed,
    float* __restrict__ out)
{
    const int n = blockIdx.x * 256 + threadIdx.x;
    float px = fminf(fmaxf(x[3 * n + 0], 0.0f), 1.0f);
    float py = fminf(fmaxf(x[3 * n + 1], 0.0f), 1.0f);
    float pz = fminf(fmaxf(x[3 * n + 2], 0.0f), 1.0f);

    const float res_tab[kLevels] = {
        16.f, 20.f, 25.f, 32.f, 40.f, 50.f, 64.f, 80.f,
        101.f, 128.f, 161.f, 203.f, 256.f, 322.f, 406.f, 512.f};

    float acc[2 * kLevels];
#pragma unroll
    for (int l = 0; l < kLevels; ++l) {
        float a0, a1;
        eval_level(px, py, pz, res_tab[l],
                   packed + (size_t)l * kTableSize, a0, a1);
        acc[2 * l + 0] = a0;
        acc[2 * l + 1] = a1;
    }
    float4* o4 = reinterpret_cast<float4*>(out + (size_t)n * (2 * kLevels));
#pragma unroll
    for (int kq = 0; kq < 8; ++kq) {
        o4[kq] = make_float4(acc[4 * kq + 0], acc[4 * kq + 1],
                             acc[4 * kq + 2], acc[4 * kq + 3]);
    }
}

extern "C" void kernel_launch(void* const* d_in, const int* in_sizes, int n_in,
                              void* d_out, int out_size, void* d_ws, size_t ws_size,
                              hipStream_t stream) {
    const float* x = (const float*)d_in[0];       // [2^21, 3] f32
    const float* tables = (const float*)d_in[1];  // [16, 2^19, 2] f32
    float* out = (float*)d_out;                   // [2^21, 32] f32

    if (ws_size >= kPackedBytes + kLvlOutBytes) {
        uint32_t* packed = (uint32_t*)d_ws;
        uint32_t* lvl_out = (uint32_t*)((char*)d_ws + kPackedBytes);
        // pass 0: 2^23 entries, 2 per thread
        hipLaunchKernelGGL(pack_tables_kernel,
                           dim3((kLevels * kTableSize / 2) / 256), dim3(256),
                           0, stream, tables, packed);
        // pass 1: 16 levels x 2048 chunks, blockIdx-ordered by level
        hipLaunchKernelGGL(level_pass_kernel,
                           dim3(kLevels * kChunksPerLevel), dim3(256),
                           0, stream, x, packed, lvl_out);
        // pass 2
        hipLaunchKernelGGL(untile_kernel, dim3(kPoints / 256), dim3(256),
                           0, stream, lvl_out, out);
    } else if (ws_size >= kPackedBytes) {
        uint32_t* packed = (uint32_t*)d_ws;
        hipLaunchKernelGGL(pack_tables_kernel,
                           dim3((kLevels * kTableSize / 2) / 256), dim3(256),
                           0, stream, tables, packed);
        hipLaunchKernelGGL(direct_packed_kernel, dim3(kPoints / 256), dim3(256),
                           0, stream, x, packed, out);
    } else {
        hipLaunchKernelGGL(direct_kernel, dim3(kPoints / 256), dim3(256),
                           0, stream, x, tables, out);
    }
}

// Round 5
// 833.134 us; speedup vs baseline: 1.7562x; 1.7562x over previous
//
#include <hip/hip_runtime.h>
#include <stdint.h>

// HashEmbedder (Instant-NGP multires hash grid), 16 levels, F=2, T=2^19,
// N = 2^21 points.
//
// Round-5 structure (bottleneck = TCP line-serialization on divergent
// gathers, ~1-2 cyc per distinct 64B line per wave access):
//   pass 0 : pack f32 tables -> bf16x2 (4B/entry).
//   pass 0b: build dense de-hashed tables for levels 0-2 (124 KB total)
//            and dense x4-grouped tables for levels 3-6 (prime_x==1 =>
//            4 consecutive-x entries per 16B group; both x-corners of a
//            voxel in ONE load). Carved into the unused packed[0..2]
//            region -> ws requirement unchanged.
//   pass A : levels 0-2 via LDS-staged dense tables (127 KB LDS/WG;
//            random LDS gathers are ~conflict-free) -> zero TCP lines.
//   pass B : levels 3-6 via dense-x4 global tables -> 4 lines/pt/level.
//   pass C : levels 7-15 hashed, level-at-a-time (8 lines/pt/level).
//   pass 2 : transpose level-major bf16x2 -> [N][32] f32. (nt hints from
//            round 4 REMOVED: they cost ~400us in this pass.)

constexpr int kLevels = 16;
constexpr int kPoints = 1 << 21;
constexpr uint32_t kTableSize = 1u << 19;
constexpr uint32_t kMask = kTableSize - 1u;
constexpr size_t kPackedBytes = (size_t)kLevels * kTableSize * 4;  // 32 MB
constexpr size_t kLvlOutBytes = (size_t)kLevels * kPoints * 4;     // 128 MB

typedef float f32x4 __attribute__((ext_vector_type(4)));
typedef uint32_t u32x4 __attribute__((ext_vector_type(4)));

// dense coarse (levels 0-2): entry counts and bases (uint32 units)
constexpr int kS0 = 17, kS1 = 21, kS2 = 26;            // res+1
constexpr int kN0 = kS0 * kS0 * kS0;                   // 4913
constexpr int kN1 = kS1 * kS1 * kS1;                   // 9261
constexpr int kN2 = kS2 * kS2 * kS2;                   // 17576
constexpr int kB1 = kN0, kB2 = kN0 + kN1;              // 4913, 14174
constexpr int kNDense = kN0 + kN1 + kN2;               // 31750

// dense-x4 (levels 3-6): group counts (res/2+1)*(res+1)^2
constexpr int kG3 = 17 * 33 * 33;    // 18513
constexpr int kG4 = 21 * 41 * 41;    // 35301
constexpr int kG5 = 26 * 51 * 51;    // 67626
constexpr int kG6 = 33 * 65 * 65;    // 139425
constexpr int kGTot = kG3 + kG4 + kG5 + kG6;           // 260865
// byte offsets of the x4 tables inside ws (after the dense012 region)
constexpr size_t kX4Base3 = 131072;
constexpr size_t kX4Base4 = kX4Base3 + (size_t)kG3 * 16;   // 427280
constexpr size_t kX4Base5 = kX4Base4 + (size_t)kG4 * 16;   // 992096
constexpr size_t kX4Base6 = kX4Base5 + (size_t)kG5 * 16;   // 2074112
// end = 4304912 < 6 MB = packed levels 0-2 region. OK.

// floor(16 * b^i), b = exp(ln(32)/15) in f64 (boundary levels round up).
__constant__ float c_res[kLevels] = {
    16.f, 20.f, 25.f, 32.f, 40.f, 50.f, 64.f, 80.f,
    101.f, 128.f, 161.f, 203.f, 256.f, 322.f, 406.f, 512.f};

__device__ __forceinline__ uint32_t bf16_rtne_hi(float f) {
    uint32_t u = __float_as_uint(f);
    return (u + 0x7FFFu + ((u >> 16) & 1u)) >> 16;
}
__device__ __forceinline__ float bflo(uint32_t e) {
    return __uint_as_float(e << 16);
}
__device__ __forceinline__ float bfhi(uint32_t e) {
    return __uint_as_float(e & 0xFFFF0000u);
}

// ---------------- pass 0: pack tables to bf16x2 ----------------
__global__ __launch_bounds__(256) void pack_tables_kernel(
    const float* __restrict__ tables, uint32_t* __restrict__ packed)
{
    const int i = blockIdx.x * 256 + threadIdx.x;  // 2 entries per thread
    const f32x4 v = reinterpret_cast<const f32x4*>(tables)[i];
    uint2 o;
    o.x = bf16_rtne_hi(v.x) | (bf16_rtne_hi(v.y) << 16);
    o.y = bf16_rtne_hi(v.z) | (bf16_rtne_hi(v.w) << 16);
    reinterpret_cast<uint2*>(packed)[i] = o;
}

// ---------------- pass 0b-1: dense de-hashed tables, levels 0-2 --------
template <int S, int LVL>
__device__ __forceinline__ void build_dense_one(
    int r, const float* __restrict__ tables, uint32_t* __restrict__ dst)
{
    const int bz = r % S;
    const int t = r / S;
    const int by = t % S;
    const int bx = t / S;
    const uint32_t h = ((uint32_t)bx ^ ((uint32_t)by * 2654435761u) ^
                        ((uint32_t)bz * 805459861u)) & kMask;
    const float* src = tables + (((size_t)LVL << 19) + h) * 2;
    dst[r] = bf16_rtne_hi(src[0]) | (bf16_rtne_hi(src[1]) << 16);
}

__global__ __launch_bounds__(256) void build_dense012_kernel(
    const float* __restrict__ tables, uint32_t* __restrict__ dense)
{
    const int idx = blockIdx.x * 256 + threadIdx.x;
    if (idx >= kNDense) return;
    if (idx < kB1)      build_dense_one<kS0, 0>(idx,       tables, dense);
    else if (idx < kB2) build_dense_one<kS1, 1>(idx - kB1, tables, dense + kB1);
    else                build_dense_one<kS2, 2>(idx - kB2, tables, dense + kB2);
}

// ---------------- pass 0b-2: dense-x4 tables, levels 3-6 ----------------
template <int S, int LVL>
__device__ __forceinline__ void build_x4_one(
    int g, const uint32_t* __restrict__ packed, u32x4* __restrict__ dst)
{
    const int bz = g % S;
    const int t = g / S;
    const int by = t % S;
    const int gx = t / S;
    const uint32_t m = ((uint32_t)by * 2654435761u) ^
                       ((uint32_t)bz * 805459861u);
    const uint32_t e = (uint32_t)(gx * 2);
    const uint32_t* tab = packed + ((size_t)LVL << 19);
    u32x4 o;
    o.x = tab[((e + 0) ^ m) & kMask];
    o.y = tab[((e + 1) ^ m) & kMask];
    o.z = tab[((e + 2) ^ m) & kMask];
    o.w = tab[((e + 3) ^ m) & kMask];
    dst[g] = o;
}

__global__ __launch_bounds__(256) void build_x4_kernel(
    const uint32_t* __restrict__ packed, char* __restrict__ ws)
{
    const int g = blockIdx.x * 256 + threadIdx.x;
    if (g >= kGTot) return;
    if (g < kG3)
        build_x4_one<33, 3>(g, packed, (u32x4*)(ws + kX4Base3));
    else if (g < kG3 + kG4)
        build_x4_one<41, 4>(g - kG3, packed, (u32x4*)(ws + kX4Base4));
    else if (g < kG3 + kG4 + kG5)
        build_x4_one<51, 5>(g - kG3 - kG4, packed, (u32x4*)(ws + kX4Base5));
    else
        build_x4_one<65, 6>(g - kG3 - kG4 - kG5, packed, (u32x4*)(ws + kX4Base6));
}

// ---------------- pass A: levels 0-2 via LDS dense tables ----------------
template <int S, int BASE, int LVL>
__device__ __forceinline__ void eval_coarse(
    const uint32_t* __restrict__ lds, float px, float py, float pz, float r,
    uint32_t* __restrict__ lvl_out, int n)
{
    const float tx = px * r, ty = py * r, tz = pz * r;
    const float fx = floorf(tx), fy = floorf(ty), fz = floorf(tz);
    const int bx = (int)fx, by = (int)fy, bz = (int)fz;
    const float rx = tx - fx, ry = ty - fy, rz = tz - fz;
    const int c = BASE + (bx * S + by) * S + bz;
    const uint32_t e000 = lds[c],             e001 = lds[c + 1];
    const uint32_t e010 = lds[c + S],         e011 = lds[c + S + 1];
    const uint32_t e100 = lds[c + S * S],     e101 = lds[c + S * S + 1];
    const uint32_t e110 = lds[c + S * S + S], e111 = lds[c + S * S + S + 1];
    const float wx1 = rx, wx0 = 1.f - rx;
    const float wy1 = ry, wy0 = 1.f - ry;
    const float wz1 = rz, wz0 = 1.f - rz;
    float a0 = 0.f, a1 = 0.f;
    a0 = fmaf(wx0 * wy0 * wz0, bflo(e000), a0);
    a1 = fmaf(wx0 * wy0 * wz0, bfhi(e000), a1);
    a0 = fmaf(wx0 * wy0 * wz1, bflo(e001), a0);
    a1 = fmaf(wx0 * wy0 * wz1, bfhi(e001), a1);
    a0 = fmaf(wx0 * wy1 * wz0, bflo(e010), a0);
    a1 = fmaf(wx0 * wy1 * wz0, bfhi(e010), a1);
    a0 = fmaf(wx0 * wy1 * wz1, bflo(e011), a0);
    a1 = fmaf(wx0 * wy1 * wz1, bfhi(e011), a1);
    a0 = fmaf(wx1 * wy0 * wz0, bflo(e100), a0);
    a1 = fmaf(wx1 * wy0 * wz0, bfhi(e100), a1);
    a0 = fmaf(wx1 * wy0 * wz1, bflo(e101), a0);
    a1 = fmaf(wx1 * wy0 * wz1, bfhi(e101), a1);
    a0 = fmaf(wx1 * wy1 * wz0, bflo(e110), a0);
    a1 = fmaf(wx1 * wy1 * wz0, bfhi(e110), a1);
    a0 = fmaf(wx1 * wy1 * wz1, bflo(e111), a0);
    a1 = fmaf(wx1 * wy1 * wz1, bfhi(e111), a1);
    lvl_out[(size_t)LVL * kPoints + n] =
        bf16_rtne_hi(a0) | (bf16_rtne_hi(a1) << 16);
}

__global__ __launch_bounds__(512) void coarse_kernel(
    const float* __restrict__ x, const uint32_t* __restrict__ dense,
    uint32_t* __restrict__ lvl_out)
{
    __shared__ uint32_t s_tab[kNDense];  // 127000 B
    for (int i = threadIdx.x; i < kNDense; i += 512) s_tab[i] = dense[i];
    __syncthreads();

    const int n0 = blockIdx.x * 2048 + threadIdx.x;
#pragma unroll
    for (int k = 0; k < 4; ++k) {
        const int n = n0 + k * 512;
        const float px = fminf(fmaxf(x[3 * n + 0], 0.0f), 1.0f);
        const float py = fminf(fmaxf(x[3 * n + 1], 0.0f), 1.0f);
        const float pz = fminf(fmaxf(x[3 * n + 2], 0.0f), 1.0f);
        eval_coarse<kS0, 0,   0>(s_tab, px, py, pz, 16.f, lvl_out, n);
        eval_coarse<kS1, kB1, 1>(s_tab, px, py, pz, 20.f, lvl_out, n);
        eval_coarse<kS2, kB2, 2>(s_tab, px, py, pz, 25.f, lvl_out, n);
    }
}

// ---------------- pass B: levels 3-6 via dense-x4 global ----------------
template <int S, int LVL>
__device__ __forceinline__ void eval_mid(
    const u32x4* __restrict__ tab, float px, float py, float pz, float r,
    uint32_t* __restrict__ lvl_out, int n)
{
    const float tx = px * r, ty = py * r, tz = pz * r;
    const float fx = floorf(tx), fy = floorf(ty), fz = floorf(tz);
    const int bx = (int)fx, by = (int)fy, bz = (int)fz;
    const float rx = tx - fx, ry = ty - fy, rz = tz - fz;
    const int gx = bx >> 1;
    const int par = bx & 1;
    const float wx1 = rx, wx0 = 1.f - rx;
    const float wy1 = ry, wy0 = 1.f - ry;
    const float wz1 = rz, wz0 = 1.f - rz;
    float a0 = 0.f, a1 = 0.f;
#pragma unroll
    for (int c = 0; c < 4; ++c) {  // bit1 -> y-corner, bit0 -> z-corner
        const int gidx = (gx * S + (by + ((c >> 1) & 1))) * S + (bz + (c & 1));
        const u32x4 g = tab[gidx];
        const uint32_t lo = par ? g.y : g.x;
        const uint32_t hi = par ? g.z : g.y;
        const float wyz = ((c & 2) ? wy1 : wy0) * ((c & 1) ? wz1 : wz0);
        a0 = fmaf(wyz, fmaf(wx0, bflo(lo), wx1 * bflo(hi)), a0);
        a1 = fmaf(wyz, fmaf(wx0, bfhi(lo), wx1 * bfhi(hi)), a1);
    }
    lvl_out[(size_t)LVL * kPoints + n] =
        bf16_rtne_hi(a0) | (bf16_rtne_hi(a1) << 16);
}

__global__ __launch_bounds__(256) void mid_kernel(
    const float* __restrict__ x, const char* __restrict__ ws,
    uint32_t* __restrict__ lvl_out)
{
    const int b = blockIdx.x;
    const int sub = b >> 11;                 // 0..3 -> level 3..6
    const int chunk = b & 2047;
    const int n0 = chunk * 1024 + threadIdx.x;
#pragma unroll
    for (int k = 0; k < 4; ++k) {
        const int n = n0 + k * 256;
        const float px = fminf(fmaxf(x[3 * n + 0], 0.0f), 1.0f);
        const float py = fminf(fmaxf(x[3 * n + 1], 0.0f), 1.0f);
        const float pz = fminf(fmaxf(x[3 * n + 2], 0.0f), 1.0f);
        if (sub == 0)
            eval_mid<33, 3>((const u32x4*)(ws + kX4Base3), px, py, pz, 32.f, lvl_out, n);
        else if (sub == 1)
            eval_mid<41, 4>((const u32x4*)(ws + kX4Base4), px, py, pz, 40.f, lvl_out, n);
        else if (sub == 2)
            eval_mid<51, 5>((const u32x4*)(ws + kX4Base5), px, py, pz, 50.f, lvl_out, n);
        else
            eval_mid<65, 6>((const u32x4*)(ws + kX4Base6), px, py, pz, 64.f, lvl_out, n);
    }
}

// ---------------- pass C: levels 7-15 hashed, level-at-a-time -----------
__device__ __forceinline__ void eval_level(
    float px, float py, float pz, float r,
    const uint32_t* __restrict__ tab, float& a0, float& a1)
{
    const float tx = px * r, ty = py * r, tz = pz * r;
    const float fx = floorf(tx), fy = floorf(ty), fz = floorf(tz);
    const int bx = (int)fx, by = (int)fy, bz = (int)fz;
    const float rx = tx - fx, ry = ty - fy, rz = tz - fz;

    const uint32_t hx0 = (uint32_t)bx;
    const uint32_t hx1 = (uint32_t)(bx + 1);
    const uint32_t hy0 = (uint32_t)by * 2654435761u;
    const uint32_t hy1 = (uint32_t)(by + 1) * 2654435761u;
    const uint32_t hz0 = (uint32_t)bz * 805459861u;
    const uint32_t hz1 = (uint32_t)(bz + 1) * 805459861u;

    const float wx1 = rx, wx0 = 1.0f - rx;
    const float wy1 = ry, wy0 = 1.0f - ry;
    const float wz1 = rz, wz0 = 1.0f - rz;

    a0 = 0.0f; a1 = 0.0f;
#pragma unroll
    for (int c = 0; c < 8; ++c) {
        const uint32_t h = (((c & 4) ? hx1 : hx0) ^
                            ((c & 2) ? hy1 : hy0) ^
                            ((c & 1) ? hz1 : hz0)) & kMask;
        const uint32_t e = tab[h];
        const float w = ((c & 4) ? wx1 : wx0) *
                        ((c & 2) ? wy1 : wy0) *
                        ((c & 1) ? wz1 : wz0);
        a0 = fmaf(w, bflo(e), a0);
        a1 = fmaf(w, bfhi(e), a1);
    }
}

__global__ __launch_bounds__(256) void fine_kernel(
    const float* __restrict__ x,
    const uint32_t* __restrict__ packed,
    uint32_t* __restrict__ lvl_out)
{
    const int b = blockIdx.x;
    const int level = 7 + (b >> 11);       // level-at-a-time machine fill
    const int chunk = b & 2047;

    const float r = c_res[level];
    const uint32_t* __restrict__ tab = packed + (size_t)level * kTableSize;
    uint32_t* __restrict__ w = lvl_out + (size_t)level * kPoints;

    const int n0 = chunk * 1024 + threadIdx.x;
#pragma unroll
    for (int k = 0; k < 4; ++k) {
        const int n = n0 + k * 256;
        const float px = fminf(fmaxf(x[3 * n + 0], 0.0f), 1.0f);
        const float py = fminf(fmaxf(x[3 * n + 1], 0.0f), 1.0f);
        const float pz = fminf(fmaxf(x[3 * n + 2], 0.0f), 1.0f);
        float a0, a1;
        eval_level(px, py, pz, r, tab, a0, a1);
        w[n] = bf16_rtne_hi(a0) | (bf16_rtne_hi(a1) << 16);
    }
}

// ---------------- pass 2: level-major bf16 -> [N][32] f32 ----------------
__global__ __launch_bounds__(256) void untile_kernel(
    const uint32_t* __restrict__ lvl_out, float* __restrict__ out)
{
    const int n = blockIdx.x * 256 + threadIdx.x;
    float vals[2 * kLevels];
#pragma unroll
    for (int l = 0; l < kLevels; ++l) {
        const uint32_t u = lvl_out[(size_t)l * kPoints + n];
        vals[2 * l + 0] = bflo(u);
        vals[2 * l + 1] = bfhi(u);
    }
    float4* o4 = reinterpret_cast<float4*>(out + (size_t)n * (2 * kLevels));
#pragma unroll
    for (int kq = 0; kq < 8; ++kq) {
        o4[kq] = make_float4(vals[4 * kq + 0], vals[4 * kq + 1],
                             vals[4 * kq + 2], vals[4 * kq + 3]);
    }
}

// ---------------- fallbacks (round-0/round-2 proven paths) --------------
__global__ __launch_bounds__(256) void direct_kernel(
    const float* __restrict__ x,
    const float* __restrict__ tables,
    float* __restrict__ out)
{
    const int n = blockIdx.x * 256 + threadIdx.x;
    float px = fminf(fmaxf(x[3 * n + 0], 0.0f), 1.0f);
    float py = fminf(fmaxf(x[3 * n + 1], 0.0f), 1.0f);
    float pz = fminf(fmaxf(x[3 * n + 2], 0.0f), 1.0f);

    const float res_tab[kLevels] = {
        16.f, 20.f, 25.f, 32.f, 40.f, 50.f, 64.f, 80.f,
        101.f, 128.f, 161.f, 203.f, 256.f, 322.f, 406.f, 512.f};

    float acc[2 * kLevels];
#pragma unroll
    for (int l = 0; l < kLevels; ++l) {
        const float r = res_tab[l];
        const float tx = px * r, ty = py * r, tz = pz * r;
        const float fx = floorf(tx), fy = floorf(ty), fz = floorf(tz);
        const int bx = (int)fx, by = (int)fy, bz = (int)fz;
        const float rx = tx - fx, ry = ty - fy, rz = tz - fz;
        const uint32_t hx0 = (uint32_t)bx;
        const uint32_t hx1 = (uint32_t)(bx + 1);
        const uint32_t hy0 = (uint32_t)by * 2654435761u;
        const uint32_t hy1 = (uint32_t)(by + 1) * 2654435761u;
        const uint32_t hz0 = (uint32_t)bz * 805459861u;
        const uint32_t hz1 = (uint32_t)(bz + 1) * 805459861u;
        const float wx1 = rx, wx0 = 1.0f - rx;
        const float wy1 = ry, wy0 = 1.0f - ry;
        const float wz1 = rz, wz0 = 1.0f - rz;
        const float2* __restrict__ tab =
            reinterpret_cast<const float2*>(tables) + (size_t)l * kTableSize;
        float a0 = 0.0f, a1 = 0.0f;
#pragma unroll
        for (int c = 0; c < 8; ++c) {
            const uint32_t h = (((c & 4) ? hx1 : hx0) ^
                                ((c & 2) ? hy1 : hy0) ^
                                ((c & 1) ? hz1 : hz0)) & kMask;
            const float2 e = tab[h];
            const float w = ((c & 4) ? wx1 : wx0) *
                            ((c & 2) ? wy1 : wy0) *
                            ((c & 1) ? wz1 : wz0);
            a0 = fmaf(w, e.x, a0);
            a1 = fmaf(w, e.y, a1);
        }
        acc[2 * l + 0] = a0;
        acc[2 * l + 1] = a1;
    }
    float4* o4 = reinterpret_cast<float4*>(out + (size_t)n * (2 * kLevels));
#pragma unroll
    for (int kq = 0; kq < 8; ++kq) {
        o4[kq] = make_float4(acc[4 * kq + 0], acc[4 * kq + 1],
                             acc[4 * kq + 2], acc[4 * kq + 3]);
    }
}

__global__ __launch_bounds__(256) void direct_packed_kernel(
    const float* __restrict__ x,
    const uint32_t* __restrict__ packed,
    float* __restrict__ out)
{
    const int n = blockIdx.x * 256 + threadIdx.x;
    float px = fminf(fmaxf(x[3 * n + 0], 0.0f), 1.0f);
    float py = fminf(fmaxf(x[3 * n + 1], 0.0f), 1.0f);
    float pz = fminf(fmaxf(x[3 * n + 2], 0.0f), 1.0f);

    const float res_tab[kLevels] = {
        16.f, 20.f, 25.f, 32.f, 40.f, 50.f, 64.f, 80.f,
        101.f, 128.f, 161.f, 203.f, 256.f, 322.f, 406.f, 512.f};

    float acc[2 * kLevels];
#pragma unroll
    for (int l = 0; l < kLevels; ++l) {
        float a0, a1;
        eval_level(px, py, pz, res_tab[l],
                   packed + (size_t)l * kTableSize, a0, a1);
        acc[2 * l + 0] = a0;
        acc[2 * l + 1] = a1;
    }
    float4* o4 = reinterpret_cast<float4*>(out + (size_t)n * (2 * kLevels));
#pragma unroll
    for (int kq = 0; kq < 8; ++kq) {
        o4[kq] = make_float4(acc[4 * kq + 0], acc[4 * kq + 1],
                             acc[4 * kq + 2], acc[4 * kq + 3]);
    }
}

extern "C" void kernel_launch(void* const* d_in, const int* in_sizes, int n_in,
                              void* d_out, int out_size, void* d_ws, size_t ws_size,
                              hipStream_t stream) {
    const float* x = (const float*)d_in[0];       // [2^21, 3] f32
    const float* tables = (const float*)d_in[1];  // [16, 2^19, 2] f32
    float* out = (float*)d_out;                   // [2^21, 32] f32

    if (ws_size >= kPackedBytes + kLvlOutBytes) {
        char* ws = (char*)d_ws;
        uint32_t* packed = (uint32_t*)ws;
        uint32_t* lvl_out = (uint32_t*)(ws + kPackedBytes);
        uint32_t* dense012 = (uint32_t*)ws;  // overlays packed[0..2] (unused)

        hipLaunchKernelGGL(pack_tables_kernel,
                           dim3((kLevels * kTableSize / 2) / 256), dim3(256),
                           0, stream, tables, packed);
        // builds overwrite the packed[0..2] region only; readers of
        // packed[3..6] (build_x4) and packed[7..15] (fine) are untouched.
        hipLaunchKernelGGL(build_dense012_kernel,
                           dim3((kNDense + 255) / 256), dim3(256),
                           0, stream, tables, dense012);
        hipLaunchKernelGGL(build_x4_kernel,
                           dim3((kGTot + 255) / 256), dim3(256),
                           0, stream, packed, ws);
        // pass A: levels 0-2 (LDS), 1024 blocks x 512 thr x 4 pts
        hipLaunchKernelGGL(coarse_kernel, dim3(kPoints / 2048), dim3(512),
                           0, stream, x, dense012, lvl_out);
        // pass B: levels 3-6 (dense-x4), 4 x 2048 blocks
        hipLaunchKernelGGL(mid_kernel, dim3(4 * 2048), dim3(256),
                           0, stream, x, (const char*)ws, lvl_out);
        // pass C: levels 7-15 (hashed), 9 x 2048 blocks
        hipLaunchKernelGGL(fine_kernel, dim3(9 * 2048), dim3(256),
                           0, stream, x, packed, lvl_out);
        // pass 2
        hipLaunchKernelGGL(untile_kernel, dim3(kPoints / 256), dim3(256),
                           0, stream, lvl_out, out);
    } else if (ws_size >= kPackedBytes) {
        uint32_t* packed = (uint32_t*)d_ws;
        hipLaunchKernelGGL(pack_tables_kernel,
                           dim3((kLevels * kTableSize / 2) / 256), dim3(256),
                           0, stream, tables, packed);
        hipLaunchKernelGGL(direct_packed_kernel, dim3(kPoints / 256), dim3(256),
                           0, stream, x, packed, out);
    } else {
        hipLaunchKernelGGL(direct_kernel, dim3(kPoints / 256), dim3(256),
                           0, stream, x, tables, out);
    }
}

// Round 6
// 575.864 us; speedup vs baseline: 2.5407x; 1.4468x over previous
//
#include <hip/hip_runtime.h>
#include <stdint.h>

// HashEmbedder (Instant-NGP multires hash grid), 16 levels, F=2, T=2^19,
// N = 2^21 points.
//
// Round-6 = round-5 + even-bx hash-pairing in fine_kernel:
//   prime_x == 1  =>  for even bx, h(bx+1,y,z) = h(bx,y,z) ^ 1, i.e. the
//   two x-corners of a voxel are an ALIGNED 8B pair in the hash table ->
//   one dwordx2 gather instead of two dword gathers (4 instead of 8 loads
//   per point) for ~half the lanes. Divergent branch keeps loads
//   exec-masked: ~384 L1 lines/wave/level vs 512 (-25% on the binding
//   TCP line-serialization resource).
//
//   pass 0 : pack f32 tables -> bf16x2 (4B/entry).
//   pass 0b: dense de-hashed tables for levels 0-2 (124 KB) and dense
//            x4-grouped tables for levels 3-6, carved into the unused
//            packed[0..2] region.
//   pass A : levels 0-2 via LDS-staged dense tables.
//   pass B : levels 3-6 via dense-x4 global tables (4 lines/pt/level).
//   pass C : levels 7-15 hashed, level-at-a-time, even-bx pairing.
//   pass 2 : transpose level-major bf16x2 -> [N][32] f32.

constexpr int kLevels = 16;
constexpr int kPoints = 1 << 21;
constexpr uint32_t kTableSize = 1u << 19;
constexpr uint32_t kMask = kTableSize - 1u;
constexpr size_t kPackedBytes = (size_t)kLevels * kTableSize * 4;  // 32 MB
constexpr size_t kLvlOutBytes = (size_t)kLevels * kPoints * 4;     // 128 MB

typedef float f32x4 __attribute__((ext_vector_type(4)));
typedef uint32_t u32x4 __attribute__((ext_vector_type(4)));

// dense coarse (levels 0-2): entry counts and bases (uint32 units)
constexpr int kS0 = 17, kS1 = 21, kS2 = 26;            // res+1
constexpr int kN0 = kS0 * kS0 * kS0;                   // 4913
constexpr int kN1 = kS1 * kS1 * kS1;                   // 9261
constexpr int kN2 = kS2 * kS2 * kS2;                   // 17576
constexpr int kB1 = kN0, kB2 = kN0 + kN1;              // 4913, 14174
constexpr int kNDense = kN0 + kN1 + kN2;               // 31750

// dense-x4 (levels 3-6): group counts (res/2+1)*(res+1)^2
constexpr int kG3 = 17 * 33 * 33;    // 18513
constexpr int kG4 = 21 * 41 * 41;    // 35301
constexpr int kG5 = 26 * 51 * 51;    // 67626
constexpr int kG6 = 33 * 65 * 65;    // 139425
constexpr int kGTot = kG3 + kG4 + kG5 + kG6;           // 260865
// byte offsets of the x4 tables inside ws (after the dense012 region)
constexpr size_t kX4Base3 = 131072;
constexpr size_t kX4Base4 = kX4Base3 + (size_t)kG3 * 16;   // 427280
constexpr size_t kX4Base5 = kX4Base4 + (size_t)kG4 * 16;   // 992096
constexpr size_t kX4Base6 = kX4Base5 + (size_t)kG5 * 16;   // 2074112
// end = 4304912 < 6 MB = packed levels 0-2 region. OK.

// floor(16 * b^i), b = exp(ln(32)/15) in f64 (boundary levels round up).
__constant__ float c_res[kLevels] = {
    16.f, 20.f, 25.f, 32.f, 40.f, 50.f, 64.f, 80.f,
    101.f, 128.f, 161.f, 203.f, 256.f, 322.f, 406.f, 512.f};

__device__ __forceinline__ uint32_t bf16_rtne_hi(float f) {
    uint32_t u = __float_as_uint(f);
    return (u + 0x7FFFu + ((u >> 16) & 1u)) >> 16;
}
__device__ __forceinline__ float bflo(uint32_t e) {
    return __uint_as_float(e << 16);
}
__device__ __forceinline__ float bfhi(uint32_t e) {
    return __uint_as_float(e & 0xFFFF0000u);
}

// ---------------- pass 0: pack tables to bf16x2 ----------------
__global__ __launch_bounds__(256) void pack_tables_kernel(
    const float* __restrict__ tables, uint32_t* __restrict__ packed)
{
    const int i = blockIdx.x * 256 + threadIdx.x;  // 2 entries per thread
    const f32x4 v = reinterpret_cast<const f32x4*>(tables)[i];
    uint2 o;
    o.x = bf16_rtne_hi(v.x) | (bf16_rtne_hi(v.y) << 16);
    o.y = bf16_rtne_hi(v.z) | (bf16_rtne_hi(v.w) << 16);
    reinterpret_cast<uint2*>(packed)[i] = o;
}

// ---------------- pass 0b-1: dense de-hashed tables, levels 0-2 --------
template <int S, int LVL>
__device__ __forceinline__ void build_dense_one(
    int r, const float* __restrict__ tables, uint32_t* __restrict__ dst)
{
    const int bz = r % S;
    const int t = r / S;
    const int by = t % S;
    const int bx = t / S;
    const uint32_t h = ((uint32_t)bx ^ ((uint32_t)by * 2654435761u) ^
                        ((uint32_t)bz * 805459861u)) & kMask;
    const float* src = tables + (((size_t)LVL << 19) + h) * 2;
    dst[r] = bf16_rtne_hi(src[0]) | (bf16_rtne_hi(src[1]) << 16);
}

__global__ __launch_bounds__(256) void build_dense012_kernel(
    const float* __restrict__ tables, uint32_t* __restrict__ dense)
{
    const int idx = blockIdx.x * 256 + threadIdx.x;
    if (idx >= kNDense) return;
    if (idx < kB1)      build_dense_one<kS0, 0>(idx,       tables, dense);
    else if (idx < kB2) build_dense_one<kS1, 1>(idx - kB1, tables, dense + kB1);
    else                build_dense_one<kS2, 2>(idx - kB2, tables, dense + kB2);
}

// ---------------- pass 0b-2: dense-x4 tables, levels 3-6 ----------------
template <int S, int LVL>
__device__ __forceinline__ void build_x4_one(
    int g, const uint32_t* __restrict__ packed, u32x4* __restrict__ dst)
{
    const int bz = g % S;
    const int t = g / S;
    const int by = t % S;
    const int gx = t / S;
    const uint32_t m = ((uint32_t)by * 2654435761u) ^
                       ((uint32_t)bz * 805459861u);
    const uint32_t e = (uint32_t)(gx * 2);
    const uint32_t* tab = packed + ((size_t)LVL << 19);
    u32x4 o;
    o.x = tab[((e + 0) ^ m) & kMask];
    o.y = tab[((e + 1) ^ m) & kMask];
    o.z = tab[((e + 2) ^ m) & kMask];
    o.w = tab[((e + 3) ^ m) & kMask];
    dst[g] = o;
}

__global__ __launch_bounds__(256) void build_x4_kernel(
    const uint32_t* __restrict__ packed, char* __restrict__ ws)
{
    const int g = blockIdx.x * 256 + threadIdx.x;
    if (g >= kGTot) return;
    if (g < kG3)
        build_x4_one<33, 3>(g, packed, (u32x4*)(ws + kX4Base3));
    else if (g < kG3 + kG4)
        build_x4_one<41, 4>(g - kG3, packed, (u32x4*)(ws + kX4Base4));
    else if (g < kG3 + kG4 + kG5)
        build_x4_one<51, 5>(g - kG3 - kG4, packed, (u32x4*)(ws + kX4Base5));
    else
        build_x4_one<65, 6>(g - kG3 - kG4 - kG5, packed, (u32x4*)(ws + kX4Base6));
}

// ---------------- pass A: levels 0-2 via LDS dense tables ----------------
template <int S, int BASE, int LVL>
__device__ __forceinline__ void eval_coarse(
    const uint32_t* __restrict__ lds, float px, float py, float pz, float r,
    uint32_t* __restrict__ lvl_out, int n)
{
    const float tx = px * r, ty = py * r, tz = pz * r;
    const float fx = floorf(tx), fy = floorf(ty), fz = floorf(tz);
    const int bx = (int)fx, by = (int)fy, bz = (int)fz;
    const float rx = tx - fx, ry = ty - fy, rz = tz - fz;
    const int c = BASE + (bx * S + by) * S + bz;
    const uint32_t e000 = lds[c],             e001 = lds[c + 1];
    const uint32_t e010 = lds[c + S],         e011 = lds[c + S + 1];
    const uint32_t e100 = lds[c + S * S],     e101 = lds[c + S * S + 1];
    const uint32_t e110 = lds[c + S * S + S], e111 = lds[c + S * S + S + 1];
    const float wx1 = rx, wx0 = 1.f - rx;
    const float wy1 = ry, wy0 = 1.f - ry;
    const float wz1 = rz, wz0 = 1.f - rz;
    float a0 = 0.f, a1 = 0.f;
    a0 = fmaf(wx0 * wy0 * wz0, bflo(e000), a0);
    a1 = fmaf(wx0 * wy0 * wz0, bfhi(e000), a1);
    a0 = fmaf(wx0 * wy0 * wz1, bflo(e001), a0);
    a1 = fmaf(wx0 * wy0 * wz1, bfhi(e001), a1);
    a0 = fmaf(wx0 * wy1 * wz0, bflo(e010), a0);
    a1 = fmaf(wx0 * wy1 * wz0, bfhi(e010), a1);
    a0 = fmaf(wx0 * wy1 * wz1, bflo(e011), a0);
    a1 = fmaf(wx0 * wy1 * wz1, bfhi(e011), a1);
    a0 = fmaf(wx1 * wy0 * wz0, bflo(e100), a0);
    a1 = fmaf(wx1 * wy0 * wz0, bfhi(e100), a1);
    a0 = fmaf(wx1 * wy0 * wz1, bflo(e101), a0);
    a1 = fmaf(wx1 * wy0 * wz1, bfhi(e101), a1);
    a0 = fmaf(wx1 * wy1 * wz0, bflo(e110), a0);
    a1 = fmaf(wx1 * wy1 * wz0, bfhi(e110), a1);
    a0 = fmaf(wx1 * wy1 * wz1, bflo(e111), a0);
    a1 = fmaf(wx1 * wy1 * wz1, bfhi(e111), a1);
    lvl_out[(size_t)LVL * kPoints + n] =
        bf16_rtne_hi(a0) | (bf16_rtne_hi(a1) << 16);
}

__global__ __launch_bounds__(512) void coarse_kernel(
    const float* __restrict__ x, const uint32_t* __restrict__ dense,
    uint32_t* __restrict__ lvl_out)
{
    __shared__ uint32_t s_tab[kNDense];  // 127000 B
    for (int i = threadIdx.x; i < kNDense; i += 512) s_tab[i] = dense[i];
    __syncthreads();

    const int n0 = blockIdx.x * 2048 + threadIdx.x;
#pragma unroll
    for (int k = 0; k < 4; ++k) {
        const int n = n0 + k * 512;
        const float px = fminf(fmaxf(x[3 * n + 0], 0.0f), 1.0f);
        const float py = fminf(fmaxf(x[3 * n + 1], 0.0f), 1.0f);
        const float pz = fminf(fmaxf(x[3 * n + 2], 0.0f), 1.0f);
        eval_coarse<kS0, 0,   0>(s_tab, px, py, pz, 16.f, lvl_out, n);
        eval_coarse<kS1, kB1, 1>(s_tab, px, py, pz, 20.f, lvl_out, n);
        eval_coarse<kS2, kB2, 2>(s_tab, px, py, pz, 25.f, lvl_out, n);
    }
}

// ---------------- pass B: levels 3-6 via dense-x4 global ----------------
template <int S, int LVL>
__device__ __forceinline__ void eval_mid(
    const u32x4* __restrict__ tab, float px, float py, float pz, float r,
    uint32_t* __restrict__ lvl_out, int n)
{
    const float tx = px * r, ty = py * r, tz = pz * r;
    const float fx = floorf(tx), fy = floorf(ty), fz = floorf(tz);
    const int bx = (int)fx, by = (int)fy, bz = (int)fz;
    const float rx = tx - fx, ry = ty - fy, rz = tz - fz;
    const int gx = bx >> 1;
    const int par = bx & 1;
    const float wx1 = rx, wx0 = 1.f - rx;
    const float wy1 = ry, wy0 = 1.f - ry;
    const float wz1 = rz, wz0 = 1.f - rz;
    float a0 = 0.f, a1 = 0.f;
#pragma unroll
    for (int c = 0; c < 4; ++c) {  // bit1 -> y-corner, bit0 -> z-corner
        const int gidx = (gx * S + (by + ((c >> 1) & 1))) * S + (bz + (c & 1));
        const u32x4 g = tab[gidx];
        const uint32_t lo = par ? g.y : g.x;
        const uint32_t hi = par ? g.z : g.y;
        const float wyz = ((c & 2) ? wy1 : wy0) * ((c & 1) ? wz1 : wz0);
        a0 = fmaf(wyz, fmaf(wx0, bflo(lo), wx1 * bflo(hi)), a0);
        a1 = fmaf(wyz, fmaf(wx0, bfhi(lo), wx1 * bfhi(hi)), a1);
    }
    lvl_out[(size_t)LVL * kPoints + n] =
        bf16_rtne_hi(a0) | (bf16_rtne_hi(a1) << 16);
}

__global__ __launch_bounds__(256) void mid_kernel(
    const float* __restrict__ x, const char* __restrict__ ws,
    uint32_t* __restrict__ lvl_out)
{
    const int b = blockIdx.x;
    const int sub = b >> 11;                 // 0..3 -> level 3..6
    const int chunk = b & 2047;
    const int n0 = chunk * 1024 + threadIdx.x;
#pragma unroll
    for (int k = 0; k < 4; ++k) {
        const int n = n0 + k * 256;
        const float px = fminf(fmaxf(x[3 * n + 0], 0.0f), 1.0f);
        const float py = fminf(fmaxf(x[3 * n + 1], 0.0f), 1.0f);
        const float pz = fminf(fmaxf(x[3 * n + 2], 0.0f), 1.0f);
        if (sub == 0)
            eval_mid<33, 3>((const u32x4*)(ws + kX4Base3), px, py, pz, 32.f, lvl_out, n);
        else if (sub == 1)
            eval_mid<41, 4>((const u32x4*)(ws + kX4Base4), px, py, pz, 40.f, lvl_out, n);
        else if (sub == 2)
            eval_mid<51, 5>((const u32x4*)(ws + kX4Base5), px, py, pz, 50.f, lvl_out, n);
        else
            eval_mid<65, 6>((const u32x4*)(ws + kX4Base6), px, py, pz, 64.f, lvl_out, n);
    }
}

// ---------------- pass C: levels 7-15 hashed, even-bx pairing -----------
__device__ __forceinline__ void eval_level_paired(
    float px, float py, float pz, float r,
    const uint32_t* __restrict__ tab, float& a0, float& a1)
{
    const float tx = px * r, ty = py * r, tz = pz * r;
    const float fx = floorf(tx), fy = floorf(ty), fz = floorf(tz);
    const int bx = (int)fx, by = (int)fy, bz = (int)fz;
    const float rx = tx - fx, ry = ty - fy, rz = tz - fz;

    const uint32_t hy0 = (uint32_t)by * 2654435761u;
    const uint32_t hy1 = (uint32_t)(by + 1) * 2654435761u;
    const uint32_t hz0 = (uint32_t)bz * 805459861u;
    const uint32_t hz1 = (uint32_t)(bz + 1) * 805459861u;
    const uint32_t bxu = (uint32_t)bx;

    const uint32_t m0 = hy0 ^ hz0, m1 = hy0 ^ hz1;
    const uint32_t m2 = hy1 ^ hz0, m3 = hy1 ^ hz1;

    uint32_t elo0, elo1, elo2, elo3, ehi0, ehi1, ehi2, ehi3;
    if ((bx & 1) == 0) {
        // even bx: h(bx+1) = h(bx)^1 -> both x-corners in one aligned
        // 8B pair at index h&~1 (order resolved by h&1).
        const uint32_t h0 = (bxu ^ m0) & kMask;
        const uint32_t h1 = (bxu ^ m1) & kMask;
        const uint32_t h2 = (bxu ^ m2) & kMask;
        const uint32_t h3 = (bxu ^ m3) & kMask;
        const uint2 p0 = *reinterpret_cast<const uint2*>(tab + (h0 & ~1u));
        const uint2 p1 = *reinterpret_cast<const uint2*>(tab + (h1 & ~1u));
        const uint2 p2 = *reinterpret_cast<const uint2*>(tab + (h2 & ~1u));
        const uint2 p3 = *reinterpret_cast<const uint2*>(tab + (h3 & ~1u));
        elo0 = (h0 & 1) ? p0.y : p0.x;  ehi0 = (h0 & 1) ? p0.x : p0.y;
        elo1 = (h1 & 1) ? p1.y : p1.x;  ehi1 = (h1 & 1) ? p1.x : p1.y;
        elo2 = (h2 & 1) ? p2.y : p2.x;  ehi2 = (h2 & 1) ? p2.x : p2.y;
        elo3 = (h3 & 1) ? p3.y : p3.x;  ehi3 = (h3 & 1) ? p3.x : p3.y;
    } else {
        const uint32_t bx1 = bxu + 1;
        elo0 = tab[(bxu ^ m0) & kMask];  ehi0 = tab[(bx1 ^ m0) & kMask];
        elo1 = tab[(bxu ^ m1) & kMask];  ehi1 = tab[(bx1 ^ m1) & kMask];
        elo2 = tab[(bxu ^ m2) & kMask];  ehi2 = tab[(bx1 ^ m2) & kMask];
        elo3 = tab[(bxu ^ m3) & kMask];  ehi3 = tab[(bx1 ^ m3) & kMask];
    }

    const float wx1 = rx, wx0 = 1.f - rx;
    const float wy1 = ry, wy0 = 1.f - ry;
    const float wz1 = rz, wz0 = 1.f - rz;
    const float w0 = wy0 * wz0, w1 = wy0 * wz1;
    const float w2 = wy1 * wz0, w3 = wy1 * wz1;

    a0 = 0.f; a1 = 0.f;
    a0 = fmaf(w0, fmaf(wx0, bflo(elo0), wx1 * bflo(ehi0)), a0);
    a1 = fmaf(w0, fmaf(wx0, bfhi(elo0), wx1 * bfhi(ehi0)), a1);
    a0 = fmaf(w1, fmaf(wx0, bflo(elo1), wx1 * bflo(ehi1)), a0);
    a1 = fmaf(w1, fmaf(wx0, bfhi(elo1), wx1 * bfhi(ehi1)), a1);
    a0 = fmaf(w2, fmaf(wx0, bflo(elo2), wx1 * bflo(ehi2)), a0);
    a1 = fmaf(w2, fmaf(wx0, bfhi(elo2), wx1 * bfhi(ehi2)), a1);
    a0 = fmaf(w3, fmaf(wx0, bflo(elo3), wx1 * bflo(ehi3)), a0);
    a1 = fmaf(w3, fmaf(wx0, bfhi(elo3), wx1 * bfhi(ehi3)), a1);
}

__global__ __launch_bounds__(256) void fine_kernel(
    const float* __restrict__ x,
    const uint32_t* __restrict__ packed,
    uint32_t* __restrict__ lvl_out)
{
    const int b = blockIdx.x;
    const int level = 7 + (b >> 11);       // level-at-a-time machine fill
    const int chunk = b & 2047;

    const float r = c_res[level];
    const uint32_t* __restrict__ tab = packed + (size_t)level * kTableSize;
    uint32_t* __restrict__ w = lvl_out + (size_t)level * kPoints;

    const int n0 = chunk * 1024 + threadIdx.x;
#pragma unroll
    for (int k = 0; k < 4; ++k) {
        const int n = n0 + k * 256;
        const float px = fminf(fmaxf(x[3 * n + 0], 0.0f), 1.0f);
        const float py = fminf(fmaxf(x[3 * n + 1], 0.0f), 1.0f);
        const float pz = fminf(fmaxf(x[3 * n + 2], 0.0f), 1.0f);
        float a0, a1;
        eval_level_paired(px, py, pz, r, tab, a0, a1);
        w[n] = bf16_rtne_hi(a0) | (bf16_rtne_hi(a1) << 16);
    }
}

// ---------------- pass 2: level-major bf16 -> [N][32] f32 ----------------
__global__ __launch_bounds__(256) void untile_kernel(
    const uint32_t* __restrict__ lvl_out, float* __restrict__ out)
{
    const int n = blockIdx.x * 256 + threadIdx.x;
    float vals[2 * kLevels];
#pragma unroll
    for (int l = 0; l < kLevels; ++l) {
        const uint32_t u = lvl_out[(size_t)l * kPoints + n];
        vals[2 * l + 0] = bflo(u);
        vals[2 * l + 1] = bfhi(u);
    }
    float4* o4 = reinterpret_cast<float4*>(out + (size_t)n * (2 * kLevels));
#pragma unroll
    for (int kq = 0; kq < 8; ++kq) {
        o4[kq] = make_float4(vals[4 * kq + 0], vals[4 * kq + 1],
                             vals[4 * kq + 2], vals[4 * kq + 3]);
    }
}

// ---------------- fallbacks (round-0/round-2 proven paths) --------------
__device__ __forceinline__ void eval_level(
    float px, float py, float pz, float r,
    const uint32_t* __restrict__ tab, float& a0, float& a1)
{
    const float tx = px * r, ty = py * r, tz = pz * r;
    const float fx = floorf(tx), fy = floorf(ty), fz = floorf(tz);
    const int bx = (int)fx, by = (int)fy, bz = (int)fz;
    const float rx = tx - fx, ry = ty - fy, rz = tz - fz;

    const uint32_t hx0 = (uint32_t)bx;
    const uint32_t hx1 = (uint32_t)(bx + 1);
    const uint32_t hy0 = (uint32_t)by * 2654435761u;
    const uint32_t hy1 = (uint32_t)(by + 1) * 2654435761u;
    const uint32_t hz0 = (uint32_t)bz * 805459861u;
    const uint32_t hz1 = (uint32_t)(bz + 1) * 805459861u;

    const float wx1 = rx, wx0 = 1.0f - rx;
    const float wy1 = ry, wy0 = 1.0f - ry;
    const float wz1 = rz, wz0 = 1.0f - rz;

    a0 = 0.0f; a1 = 0.0f;
#pragma unroll
    for (int c = 0; c < 8; ++c) {
        const uint32_t h = (((c & 4) ? hx1 : hx0) ^
                            ((c & 2) ? hy1 : hy0) ^
                            ((c & 1) ? hz1 : hz0)) & kMask;
        const uint32_t e = tab[h];
        const float w = ((c & 4) ? wx1 : wx0) *
                        ((c & 2) ? wy1 : wy0) *
                        ((c & 1) ? wz1 : wz0);
        a0 = fmaf(w, bflo(e), a0);
        a1 = fmaf(w, bfhi(e), a1);
    }
}

__global__ __launch_bounds__(256) void direct_kernel(
    const float* __restrict__ x,
    const float* __restrict__ tables,
    float* __restrict__ out)
{
    const int n = blockIdx.x * 256 + threadIdx.x;
    float px = fminf(fmaxf(x[3 * n + 0], 0.0f), 1.0f);
    float py = fminf(fmaxf(x[3 * n + 1], 0.0f), 1.0f);
    float pz = fminf(fmaxf(x[3 * n + 2], 0.0f), 1.0f);

    const float res_tab[kLevels] = {
        16.f, 20.f, 25.f, 32.f, 40.f, 50.f, 64.f, 80.f,
        101.f, 128.f, 161.f, 203.f, 256.f, 322.f, 406.f, 512.f};

    float acc[2 * kLevels];
#pragma unroll
    for (int l = 0; l < kLevels; ++l) {
        const float r = res_tab[l];
        const float tx = px * r, ty = py * r, tz = pz * r;
        const float fx = floorf(tx), fy = floorf(ty), fz = floorf(tz);
        const int bx = (int)fx, by = (int)fy, bz = (int)fz;
        const float rx = tx - fx, ry = ty - fy, rz = tz - fz;
        const uint32_t hx0 = (uint32_t)bx;
        const uint32_t hx1 = (uint32_t)(bx + 1);
        const uint32_t hy0 = (uint32_t)by * 2654435761u;
        const uint32_t hy1 = (uint32_t)(by + 1) * 2654435761u;
        const uint32_t hz0 = (uint32_t)bz * 805459861u;
        const uint32_t hz1 = (uint32_t)(bz + 1) * 805459861u;
        const float wx1 = rx, wx0 = 1.0f - rx;
        const float wy1 = ry, wy0 = 1.0f - ry;
        const float wz1 = rz, wz0 = 1.0f - rz;
        const float2* __restrict__ tab =
            reinterpret_cast<const float2*>(tables) + (size_t)l * kTableSize;
        float a0 = 0.0f, a1 = 0.0f;
#pragma unroll
        for (int c = 0; c < 8; ++c) {
            const uint32_t h = (((c & 4) ? hx1 : hx0) ^
                                ((c & 2) ? hy1 : hy0) ^
                                ((c & 1) ? hz1 : hz0)) & kMask;
            const float2 e = tab[h];
            const float w = ((c & 4) ? wx1 : wx0) *
                            ((c & 2) ? wy1 : wy0) *
                            ((c & 1) ? wz1 : wz0);
            a0 = fmaf(w, e.x, a0);
            a1 = fmaf(w, e.y, a1);
        }
        acc[2 * l + 0] = a0;
        acc[2 * l + 1] = a1;
    }
    float4* o4 = reinterpret_cast<float4*>(out + (size_t)n * (2 * kLevels));
#pragma unroll
    for (int kq = 0; kq < 8; ++kq) {
        o4[kq] = make_float4(acc[4 * kq + 0], acc[4 * kq + 1],
                             acc[4 * kq + 2], acc[4 * kq + 3]);
    }
}

__global__ __launch_bounds__(256) void direct_packed_kernel(
    const float* __restrict__ x,
    const uint32_t* __restrict__ packed,
    float* __restrict__ out)
{
    const int n = blockIdx.x * 256 + threadIdx.x;
    float px = fminf(fmaxf(x[3 * n + 0], 0.0f), 1.0f);
    float py = fminf(fmaxf(x[3 * n + 1], 0.0f), 1.0f);
    float pz = fminf(fmaxf(x[3 * n + 2], 0.0f), 1.0f);

    const float res_tab[kLevels] = {
        16.f, 20.f, 25.f, 32.f, 40.f, 50.f, 64.f, 80.f,
        101.f, 128.f, 161.f, 203.f, 256.f, 322.f, 406.f, 512.f};

    float acc[2 * kLevels];
#pragma unroll
    for (int l = 0; l < kLevels; ++l) {
        float a0, a1;
        eval_level(px, py, pz, res_tab[l],
                   packed + (size_t)l * kTableSize, a0, a1);
        acc[2 * l + 0] = a0;
        acc[2 * l + 1] = a1;
    }
    float4* o4 = reinterpret_cast<float4*>(out + (size_t)n * (2 * kLevels));
#pragma unroll
    for (int kq = 0; kq < 8; ++kq) {
        o4[kq] = make_float4(acc[4 * kq + 0], acc[4 * kq + 1],
                             acc[4 * kq + 2], acc[4 * kq + 3]);
    }
}

extern "C" void kernel_launch(void* const* d_in, const int* in_sizes, int n_in,
                              void* d_out, int out_size, void* d_ws, size_t ws_size,
                              hipStream_t stream) {
    const float* x = (const float*)d_in[0];       // [2^21, 3] f32
    const float* tables = (const float*)d_in[1];  // [16, 2^19, 2] f32
    float* out = (float*)d_out;                   // [2^21, 32] f32

    if (ws_size >= kPackedBytes + kLvlOutBytes) {
        char* ws = (char*)d_ws;
        uint32_t* packed = (uint32_t*)ws;
        uint32_t* lvl_out = (uint32_t*)(ws + kPackedBytes);
        uint32_t* dense012 = (uint32_t*)ws;  // overlays packed[0..2] (unused)

        hipLaunchKernelGGL(pack_tables_kernel,
                           dim3((kLevels * kTableSize / 2) / 256), dim3(256),
                           0, stream, tables, packed);
        // builds overwrite the packed[0..2] region only; readers of
        // packed[3..6] (build_x4) and packed[7..15] (fine) are untouched.
        hipLaunchKernelGGL(build_dense012_kernel,
                           dim3((kNDense + 255) / 256), dim3(256),
                           0, stream, tables, dense012);
        hipLaunchKernelGGL(build_x4_kernel,
                           dim3((kGTot + 255) / 256), dim3(256),
                           0, stream, packed, ws);
        // pass A: levels 0-2 (LDS), 1024 blocks x 512 thr x 4 pts
        hipLaunchKernelGGL(coarse_kernel, dim3(kPoints / 2048), dim3(512),
                           0, stream, x, dense012, lvl_out);
        // pass B: levels 3-6 (dense-x4), 4 x 2048 blocks
        hipLaunchKernelGGL(mid_kernel, dim3(4 * 2048), dim3(256),
                           0, stream, x, (const char*)ws, lvl_out);
        // pass C: levels 7-15 (hashed, paired), 9 x 2048 blocks
        hipLaunchKernelGGL(fine_kernel, dim3(9 * 2048), dim3(256),
                           0, stream, x, packed, lvl_out);
        // pass 2
        hipLaunchKernelGGL(untile_kernel, dim3(kPoints / 256), dim3(256),
                           0, stream, lvl_out, out);
    } else if (ws_size >= kPackedBytes) {
        uint32_t* packed = (uint32_t*)d_ws;
        hipLaunchKernelGGL(pack_tables_kernel,
                           dim3((kLevels * kTableSize / 2) / 256), dim3(256),
                           0, stream, tables, packed);
        hipLaunchKernelGGL(direct_packed_kernel, dim3(kPoints / 256), dim3(256),
                           0, stream, x, packed, out);
    } else {
        hipLaunchKernelGGL(direct_kernel, dim3(kPoints / 256), dim3(256),
                           0, stream, x, tables, out);
    }
}